// Round 17
// baseline (192.134 us; speedup 1.0000x reference)
//
#include <hip/hip_runtime.h>

// ---------------------------------------------------------------------------
// Channel_Seq_Big_Attention: B=8,N=128,M=8,D=512,H=8,DH=64, INNER=512
// Softmax is over axis=2 of (b,h,i,j,m,z) == QUERY seq axis i.
// Pipeline (fp16 compute, fp32 accumulate):
//   1. k_prep_small: x->xh f16 | w_q,w_kv -> wqkvT [n][k] (vectorized).
//   2. k_qkv_gemm (merged, serial-packed, r12-proven): blk<768 = QKV GEMM
//      (async swizzled staging, XCD-chunked); blk>=768 = w_out transpose in
//      64x64 tiles. Scatter: Qb [bh][m][i][d] (log2e/8), Kb [bh][z][j][d],
//      VbT [bh][d][m*128+j]
//   3. attention v2: block=(bh,z), 512 threads, bh=blk&63 (XCD-local).
//      lds_q + lds_p only (50KB -> 3 blocks/CU, 24 waves); V-fragments read
//      directly from global VbT (L2-hot, r3-proven pattern); 2 barriers/m.
//   4. final GEMM split-K=4, XCD-chunked, swizzled staging, fp16 partials
//      -> k_reduce4 (+bias) -> y (f32)
// Lessons encoded:
//  - r7/r8: do NOT fuse f32->f16 convert into GEMM staging (sync chain).
//  - r9/r10: linear [row][64] LDS tiles = 16-way b128 conflicts; fix =
//    pre-swizzled global source + swizzled read.
//  - r6: 2-barrier attn w/ V-double-buffer failed; cause unknown. The v2
//    here removes lds_v entirely instead (different hazard structure,
//    ledger re-verified: lds_q W-A-R spans B2->B1; lds_p PV-reads complete
//    before B1 via lgkmcnt-before-MFMA + barrier).
//  - r12/r13: co-residency != overlap; forced interleave is worse.
//  - r14: attn conflicts (3.67M) invariant to lds_p layout (shfl_xor ds-ops).
//  - r15/r16: transpose write-segmentation theory dead: 256x32 tiles with
//    conflict-free LDS still slower than 64x64 (53.4 vs 50.5). Keep 64x64.
// ---------------------------------------------------------------------------

typedef _Float16 h16;
typedef _Float16 h16x4 __attribute__((ext_vector_type(4)));
typedef _Float16 h16x8 __attribute__((ext_vector_type(8)));
typedef float f32x4 __attribute__((ext_vector_type(4)));

#define MFMA16(a, b, c) __builtin_amdgcn_mfma_f32_16x16x32_f16(a, b, c, 0, 0, 0)

// async global->LDS, 16B per lane; lds dest must be wave-uniform base
__device__ __forceinline__ void gload16(const h16* g, h16* l) {
  __builtin_amdgcn_global_load_lds(
      (const __attribute__((address_space(1))) void*)g,
      (__attribute__((address_space(3))) void*)l, 16, 0, 0);
}

// ---------------- prep kernel (x convert + wqkv transpose) ----------------
// blocks [0,2048): x->xh convert; [2048,2112): w_q T; [2112,2240): w_kv T
__global__ __launch_bounds__(256) void k_prep_small(const float* __restrict__ x,
                                                    h16* __restrict__ xh,
                                                    const float* __restrict__ w_q,
                                                    const float* __restrict__ w_kv,
                                                    h16* __restrict__ wqkvT) {
  __shared__ h16 tile[64][68];
  int blk = blockIdx.x, tid = threadIdx.x;
  if (blk < 2048) {  // convert branch (no barrier used)
    int idx = blk * 256 + tid;
    const float4* s4 = (const float4*)x;
    float4 a = s4[idx * 2];
    float4 b = s4[idx * 2 + 1];
    h16x8 o;
    o[0] = (h16)a.x; o[1] = (h16)a.y; o[2] = (h16)a.z; o[3] = (h16)a.w;
    o[4] = (h16)b.x; o[5] = (h16)b.y; o[6] = (h16)b.z; o[7] = (h16)b.w;
    *(h16x8*)&xh[(size_t)idx * 8] = o;
    return;
  }
  const float* src; h16* dst; int R, C, bx, by;
  if (blk < 2112) {
    int b2 = blk - 2048; src = w_q; dst = wqkvT; R = 512; C = 512;
    bx = b2 & 7; by = b2 >> 3;
  } else {
    int b2 = blk - 2112; src = w_kv; dst = wqkvT + 512 * 512; R = 512; C = 1024;
    bx = b2 & 15; by = b2 >> 4;
  }
  int r0 = by * 64, c0 = bx * 64;
  int lr = tid >> 4, lc = (tid & 15) * 4;
#pragma unroll
  for (int s = 0; s < 4; ++s) {
    int r = lr + s * 16;
    float4 v = *(const float4*)&src[(size_t)(r0 + r) * C + c0 + lc];
    h16x4 hq;
    hq[0] = (h16)v.x; hq[1] = (h16)v.y; hq[2] = (h16)v.z; hq[3] = (h16)v.w;
    *(h16x4*)&tile[r][lc] = hq;
  }
  __syncthreads();
  int oc = tid >> 3, os = (tid & 7) * 8;
#pragma unroll
  for (int s = 0; s < 2; ++s) {
    int c = oc + s * 32;
    h16x8 hv;
#pragma unroll
    for (int e = 0; e < 8; ++e) hv[e] = tile[os + e][c];
    *(h16x8*)&dst[(size_t)(c0 + c) * R + r0 + os] = hv;
  }
}

// ------- QKV GEMM + serial-packed w_out transpose (r12 64x64 form) --------
// blk < 768: GEMM A = xh (8192x512 f16), Bt = wqkvT, scatter epilogue.
// blk >= 768: 64x64 transpose tile of w_out (4096x4096 f32) -> woutT f16.
__global__ __launch_bounds__(256, 3) void k_qkv_gemm(const h16* __restrict__ A,
                                                     const h16* __restrict__ Bt,
                                                     const float* __restrict__ w_out,
                                                     h16* __restrict__ Qb,
                                                     h16* __restrict__ Kb,
                                                     h16* __restrict__ VbT,
                                                     h16* __restrict__ woutT) {
  __shared__ __align__(16) h16 As[128 * 64];
  __shared__ __align__(16) h16 Bs[128 * 64];
  int tid = threadIdx.x;

  if (blockIdx.x >= 768) {  // ---- w_out transpose tile (reuses As as LDS) ----
    h16(*tile)[68] = (h16(*)[68])As;
    int b2 = blockIdx.x - 768;
    int bx = b2 & 63, by = b2 >> 6;
    int r0 = by * 64, c0 = bx * 64;
    int lr = tid >> 4, lc = (tid & 15) * 4;
#pragma unroll
    for (int s = 0; s < 4; ++s) {
      int r = lr + s * 16;
      float4 v = *(const float4*)&w_out[(size_t)(r0 + r) * 4096 + c0 + lc];
      h16x4 hq;
      hq[0] = (h16)v.x; hq[1] = (h16)v.y; hq[2] = (h16)v.z; hq[3] = (h16)v.w;
      *(h16x4*)&tile[r][lc] = hq;
    }
    __syncthreads();
    int oc = tid >> 3, os = (tid & 7) * 8;
#pragma unroll
    for (int s = 0; s < 2; ++s) {
      int c = oc + s * 32;
      h16x8 hv;
#pragma unroll
      for (int e = 0; e < 8; ++e) hv[e] = tile[os + e][c];
      *(h16x8*)&woutT[(size_t)(c0 + c) * 4096 + r0 + os] = hv;
    }
    return;
  }

  // ---- GEMM branch: XCD-chunked (XCD k owns tileM [k*8,k*8+8) x 12 tileN) --
  int lg = (blockIdx.x & 7) * 96 + (blockIdx.x >> 3);
  int tileM = lg / 12, tileN = lg % 12;
  int w = tid >> 6, l = tid & 63, g = l >> 4, t = l & 15;
  int wr = w >> 1, wc = w & 1;
  int lr = l >> 3, lch = l & 7;  // staging: row-in-chunk, chunk idx
  const h16* Abase = A + (size_t)(tileM * 128) * 512;
  const h16* Bbase = Bt + (size_t)(tileN * 128) * 512;
  f32x4 acc[4][4];
#pragma unroll
  for (int i = 0; i < 4; ++i)
#pragma unroll
    for (int j = 0; j < 4; ++j) acc[i][j] = (f32x4){0.f, 0.f, 0.f, 0.f};

  for (int k0 = 0; k0 < 512; k0 += 64) {
#pragma unroll
    for (int c = 0; c < 4; ++c) {
      int chunk = w * 4 + c, row = chunk * 8 + lr;
      int sc = (lch ^ (row & 7)) * 8;  // pre-swizzled source chunk
      gload16(Abase + (size_t)row * 512 + k0 + sc, &As[chunk * 512]);
      gload16(Bbase + (size_t)row * 512 + k0 + sc, &Bs[chunk * 512]);
    }
    __syncthreads();
#pragma unroll
    for (int kk = 0; kk < 64; kk += 32) {
      h16x8 af[4], bfr[4];
#pragma unroll
      for (int mi = 0; mi < 4; ++mi) {
        int rr = wr * 64 + mi * 16 + t, c = (kk >> 3) + g;
        af[mi] = *(const h16x8*)&As[rr * 64 + ((c ^ (rr & 7)) << 3)];
      }
#pragma unroll
      for (int ni = 0; ni < 4; ++ni) {
        int rr = wc * 64 + ni * 16 + t, c = (kk >> 3) + g;
        bfr[ni] = *(const h16x8*)&Bs[rr * 64 + ((c ^ (rr & 7)) << 3)];
      }
#pragma unroll
      for (int mi = 0; mi < 4; ++mi)
#pragma unroll
        for (int ni = 0; ni < 4; ++ni) acc[mi][ni] = MFMA16(af[mi], bfr[ni], acc[mi][ni]);
    }
    __syncthreads();
  }
  // scatter epilogue: C<512 -> Q (scaled by log2e/8), C<1024 -> K, else -> V^T
#pragma unroll
  for (int mi = 0; mi < 4; ++mi) {
#pragma unroll
    for (int ni = 0; ni < 4; ++ni) {
      int C = tileN * 128 + wc * 64 + ni * 16 + t;
#pragma unroll
      for (int r = 0; r < 4; ++r) {
        int R = tileM * 128 + wr * 64 + mi * 16 + 4 * g + r;
        float val = acc[mi][ni][r];
        int b = R >> 10, rm = R & 1023;
        int i = rm >> 3, m = rm & 7;
        int bh8 = b * 8;
        if (C < 512) {
          int h = C >> 6, d = C & 63;
          Qb[((size_t)(bh8 + h) * 8 + m) * 8192 + i * 64 + d] = (h16)(val * 0.18033688f);
        } else if (C < 1024) {
          int c2 = C - 512, h = c2 >> 6, d = c2 & 63;
          Kb[((size_t)(bh8 + h) * 1024 + (m * 128 + i)) * 64 + d] = (h16)val;
        } else {
          int c2 = C - 1024, h = c2 >> 6, d = c2 & 63;
          VbT[((size_t)(bh8 + h) * 64 + d) * 1024 + (m * 128 + i)] = (h16)val;
        }
      }
    }
  }
}

// ---------------- attention v2: no lds_v, 2 barriers, 3 blocks/CU ----------
// grid 512; bh = blk&63 (same bh -> same XCD-L2), z = blk>>6.
// 512 threads = 8 waves; LDS = lds_q 16KB + lds_p 34.8KB = 50KB.
// V-fragments read directly from global VbT (L2-hot, r3-proven indexing).
// Hazard ledger (2 barriers/m): lds_q read(m) < B2 < DMA-issue(m+1),
// drained at B1(m+1). lds_p: PV ds_reads complete before wave reaches
// B1(m+1) (lgkmcnt before MFMA), B1 orders them before P-write(m+1).
__global__ __launch_bounds__(512, 6) void k_attn(const h16* __restrict__ Qbuf,
                                                 const h16* __restrict__ Kbuf,
                                                 const h16* __restrict__ VbT,
                                                 h16* __restrict__ Ob) {
  __shared__ __align__(16) h16 lds_q[128 * 64];   // Q_m [i][dh], swizzled, 16KB
  __shared__ __align__(16) h16 lds_p[128][136];   // P^T [i][j], padded, 34.8KB
  int blk = blockIdx.x;
  int bh = blk & 63, z = blk >> 6;
  int b = bh >> 3, h = bh & 7;
  const h16* Qb = Qbuf + (size_t)bh * 65536;              // [m][i][d]
  const h16* Kz = Kbuf + (size_t)bh * 65536 + z * 8192;   // [j][d]
  const h16* Vb = VbT + (size_t)bh * 65536;               // [d][u=m*128+j]
  int tid = threadIdx.x, w = tid >> 6, l = tid & 63, g = l >> 4, t = l & 15;

  int qs_r0 = l >> 3, qs_ch = l & 7;    // Q staging: 8 rows/KB, chunk of 8 h16

  // K fragments in registers, loaded ONCE (z-fixed; wave w owns 16 j-rows)
  h16x8 kf[2];
#pragma unroll
  for (int kk = 0; kk < 2; ++kk)
    kf[kk] = *(const h16x8*)&Kz[(w * 16 + t) * 64 + kk * 32 + g * 8];

  f32x4 oa[4];
#pragma unroll
  for (int dt = 0; dt < 4; ++dt) oa[dt] = (f32x4){0.f, 0.f, 0.f, 0.f};

  // prologue: stage Q_0
#pragma unroll
  for (int s = 0; s < 2; ++s) {
    int r = w * 16 + s * 8 + qs_r0;
    gload16(Qb + r * 64 + ((qs_ch ^ (r & 7)) << 3), &lds_q[(w * 16 + s * 8) * 64]);
  }

  for (int m = 0; m < 8; ++m) {
    __syncthreads();  // B1: Q[m] DMA visible; P-write(m) safe vs PV(m-1)

    // T = K_z @ Q_m^T : wave w -> j-rows [w*16,+16) x 128 i-cols
    f32x4 accS[8];
#pragma unroll
    for (int nt = 0; nt < 8; ++nt) accS[nt] = (f32x4){0.f, 0.f, 0.f, 0.f};
#pragma unroll
    for (int kk = 0; kk < 2; ++kk)
#pragma unroll
      for (int nt = 0; nt < 8; ++nt) {
        int rr = nt * 16 + t, c = kk * 4 + g;
        h16x8 bq = *(const h16x8*)&lds_q[rr * 64 + ((c ^ (rr & 7)) << 3)];
        accS[nt] = MFMA16(kf[kk], bq, accS[nt]);
      }

    // softmax over i (cols): in-reg over nt + 16 t-lanes via shfl; no max-sub
    float inv[4];
#pragma unroll
    for (int r = 0; r < 4; ++r) {
      float sum = 0.f;
#pragma unroll
      for (int nt = 0; nt < 8; ++nt) {
        float p = exp2f(accS[nt][r]);
        accS[nt][r] = p;
        sum += p;
      }
#pragma unroll
      for (int msk = 1; msk < 16; msk <<= 1) sum += __shfl_xor(sum, msk);
      inv[r] = 1.f / sum;
    }
    // normalize + cvt + P^T write: lds_p[i = nt*16+t][j = w*16+4g+r]
#pragma unroll
    for (int nt = 0; nt < 8; ++nt) {
      h16x4 pk;
#pragma unroll
      for (int r = 0; r < 4; ++r) pk[r] = (h16)(accS[nt][r] * inv[r]);
      *(h16x4*)&lds_p[nt * 16 + t][w * 16 + 4 * g] = pk;
    }
    __syncthreads();  // B2: lds_p ready; lds_q consumed

    // issue Q[m+1] DMA (drains at B1 of m+1, hidden under PV)
    if (m < 7) {
      const h16* Qm = Qb + (m + 1) * 8192;
#pragma unroll
      for (int s = 0; s < 2; ++s) {
        int r = w * 16 + s * 8 + qs_r0;
        gload16(Qm + r * 64 + ((qs_ch ^ (r & 7)) << 3), &lds_q[(w * 16 + s * 8) * 64]);
      }
    }

    // PV: out[i][d] += sum_j P^T[j][i] * V_m[j][d]; wave w -> i-rows [w*16,+16)
    // V fragments straight from global (L2-hot; r3-proven indexing)
    const h16* Vbm = Vb + m * 128;
#pragma unroll
    for (int kk = 0; kk < 4; ++kk) {
      h16x8 ap = *(const h16x8*)&lds_p[w * 16 + t][kk * 32 + g * 8];
#pragma unroll
      for (int dt = 0; dt < 4; ++dt) {
        h16x8 vf = *(const h16x8*)&Vbm[(size_t)(dt * 16 + t) * 1024 + kk * 32 + g * 8];
        oa[dt] = MFMA16(ap, vf, oa[dt]);
      }
    }
    // no third barrier: next write to lds_p is after B1(m+1)
  }

  // store out_z: Ob[b*128 + i][z*512 + h*64 + d]
#pragma unroll
  for (int dt = 0; dt < 4; ++dt)
#pragma unroll
    for (int r = 0; r < 4; ++r) {
      int i = w * 16 + 4 * g + r;
      Ob[(size_t)(b * 128 + i) * 4096 + z * 512 + h * 64 + dt * 16 + t] = (h16)oa[dt][r];
    }
}

// ---------------- final projection GEMM, split-K=4, swizzled staging ------
// A = Ob (1024x4096), Bt = woutT (4096 x 4096). Grid 1024 = 4 blocks/CU.
// XCD k gets tileN in [k*4, k*4+4) -> per-XCD woutT slice 4MB, L2-resident.
__global__ __launch_bounds__(256, 4) void k_final_gemm(const h16* __restrict__ A,
                                                       const h16* __restrict__ Bt,
                                                       h16* __restrict__ P) {
  __shared__ __align__(16) h16 As[128 * 64];
  __shared__ __align__(16) h16 Bs[128 * 64];
  int tid = threadIdx.x;
  int lg = (blockIdx.x & 7) * 128 + (blockIdx.x >> 3);
  int tileN = lg >> 5;        // [xcd*4, xcd*4+4)
  int rem = lg & 31;
  int tileM = rem >> 2, ks = rem & 3;
  int w = tid >> 6, l = tid & 63, g = l >> 4, t = l & 15;
  int wr = w >> 1, wc = w & 1;
  int lr = l >> 3, lch = l & 7;
  const h16* Abase = A + (size_t)(tileM * 128) * 4096 + ks * 1024;
  const h16* Bbase = Bt + (size_t)(tileN * 128) * 4096 + ks * 1024;
  f32x4 acc[4][4];
#pragma unroll
  for (int i = 0; i < 4; ++i)
#pragma unroll
    for (int j = 0; j < 4; ++j) acc[i][j] = (f32x4){0.f, 0.f, 0.f, 0.f};

  for (int k0 = 0; k0 < 1024; k0 += 64) {
#pragma unroll
    for (int c = 0; c < 4; ++c) {
      int chunk = w * 4 + c, row = chunk * 8 + lr;
      int sc = (lch ^ (row & 7)) * 8;  // pre-swizzled source chunk
      gload16(Abase + (size_t)row * 4096 + k0 + sc, &As[chunk * 512]);
      gload16(Bbase + (size_t)row * 4096 + k0 + sc, &Bs[chunk * 512]);
    }
    __syncthreads();
#pragma unroll
    for (int kk = 0; kk < 64; kk += 32) {
      h16x8 af[4], bfr[4];
#pragma unroll
      for (int mi = 0; mi < 4; ++mi) {
        int rr = wr * 64 + mi * 16 + t, c = (kk >> 3) + g;
        af[mi] = *(const h16x8*)&As[rr * 64 + ((c ^ (rr & 7)) << 3)];
      }
#pragma unroll
      for (int ni = 0; ni < 4; ++ni) {
        int rr = wc * 64 + ni * 16 + t, c = (kk >> 3) + g;
        bfr[ni] = *(const h16x8*)&Bs[rr * 64 + ((c ^ (rr & 7)) << 3)];
      }
#pragma unroll
      for (int mi = 0; mi < 4; ++mi)
#pragma unroll
        for (int ni = 0; ni < 4; ++ni) acc[mi][ni] = MFMA16(af[mi], bfr[ni], acc[mi][ni]);
    }
    __syncthreads();
  }
  h16* Pk = P + (size_t)ks * 4194304;
#pragma unroll
  for (int mi = 0; mi < 4; ++mi) {
#pragma unroll
    for (int ni = 0; ni < 4; ++ni) {
      int C = tileN * 128 + wc * 64 + ni * 16 + t;
#pragma unroll
      for (int r = 0; r < 4; ++r) {
        int R = tileM * 128 + wr * 64 + mi * 16 + 4 * g + r;
        Pk[(size_t)R * 4096 + C] = (h16)acc[mi][ni][r];
      }
    }
  }
}

// y = p0+p1+p2+p3 + bias; 8 elems/thread, grid 2048
__global__ __launch_bounds__(256) void k_reduce4(const h16* __restrict__ P,
                                                 const float* __restrict__ bias,
                                                 float* __restrict__ Y) {
  int idx = blockIdx.x * 256 + threadIdx.x;
  size_t base = (size_t)idx * 8;
  h16x8 p0 = *(const h16x8*)&P[base];
  h16x8 p1 = *(const h16x8*)&P[base + 4194304];
  h16x8 p2 = *(const h16x8*)&P[base + 8388608];
  h16x8 p3 = *(const h16x8*)&P[base + 12582912];
  int cb = (int)(base & 4095);
  float4 b0 = *(const float4*)&bias[cb];
  float4 b1 = *(const float4*)&bias[cb + 4];
  float4 o0, o1;
  o0.x = (float)p0[0] + (float)p1[0] + (float)p2[0] + (float)p3[0] + b0.x;
  o0.y = (float)p0[1] + (float)p1[1] + (float)p2[1] + (float)p3[1] + b0.y;
  o0.z = (float)p0[2] + (float)p1[2] + (float)p2[2] + (float)p3[2] + b0.z;
  o0.w = (float)p0[3] + (float)p1[3] + (float)p2[3] + (float)p3[3] + b0.w;
  o1.x = (float)p0[4] + (float)p1[4] + (float)p2[4] + (float)p3[4] + b1.x;
  o1.y = (float)p0[5] + (float)p1[5] + (float)p2[5] + (float)p3[5] + b1.y;
  o1.z = (float)p0[6] + (float)p1[6] + (float)p2[6] + (float)p3[6] + b1.z;
  o1.w = (float)p0[7] + (float)p1[7] + (float)p2[7] + (float)p3[7] + b1.w;
  *(float4*)&Y[base] = o0;
  *(float4*)&Y[base + 4] = o1;
}

// ---------------- launch ----------------

extern "C" void kernel_launch(void* const* d_in, const int* in_sizes, int n_in,
                              void* d_out, int out_size, void* d_ws, size_t ws_size,
                              hipStream_t stream) {
  const float* x = (const float*)d_in[0];
  const float* w_q = (const float*)d_in[1];
  const float* w_kv = (const float*)d_in[2];
  const float* w_out = (const float*)d_in[3];
  const float* b_out = (const float*)d_in[4];
  float* y = (float*)d_out;

  char* ws = (char*)d_ws;
  h16* woutT = (h16*)(ws + 0);          // 32 MB  (alive to the end)
  h16* Ob    = (h16*)(ws + 33554432);   //  8 MB  (alive to the end)
  h16* xh    = (h16*)(ws + 41943040);   //  8 MB  (dead after qkv)
  h16* wqkvT = (h16*)(ws + 50331648);   //  1.5MB (dead after qkv)
  h16* Qb    = (h16*)(ws + 51904512);   //  8 MB  (dead after attn)
  h16* Kb    = (h16*)(ws + 60293120);   //  8 MB  (dead after attn)
  h16* VbT   = (h16*)(ws + 68681728);   //  8 MB  (dead after attn)
  h16* Pp    = (h16*)(ws + 41943040);   // 32 MB partials, overlays dead region
  (void)ws_size; (void)in_sizes; (void)n_in; (void)out_size;

  k_prep_small<<<dim3(2240), dim3(256), 0, stream>>>(x, xh, w_q, w_kv, wqkvT);
  k_qkv_gemm<<<dim3(4864), dim3(256), 0, stream>>>(xh, wqkvT, w_out, Qb, Kb, VbT, woutT);
  k_attn<<<dim3(512), dim3(512), 0, stream>>>(Qb, Kb, VbT, Ob);
  k_final_gemm<<<dim3(1024), dim3(256), 0, stream>>>(Ob, woutT, Pp);
  k_reduce4<<<dim3(2048), dim3(256), 0, stream>>>(Pp, b_out, y);
}

// Round 18
// 179.118 us; speedup vs baseline: 1.0727x; 1.0727x over previous
//
#include <hip/hip_runtime.h>

// ---------------------------------------------------------------------------
// Channel_Seq_Big_Attention: B=8,N=128,M=8,D=512,H=8,DH=64, INNER=512
// Softmax is over axis=2 of (b,h,i,j,m,z) == QUERY seq axis i.
// Pipeline (fp16 compute, fp32 accumulate):
//   1. k_prep_small: x->xh f16 | w_q,w_kv -> wqkvT [n][k] (vectorized).
//   2. k_qkv_gemm (merged, serial-packed, r12-proven): blk<768 = QKV GEMM
//      (async swizzled staging, XCD-chunked); blk>=768 = w_out transpose in
//      64x64 tiles. Scatter: Qb [bh][m][i][d] (log2e/8), Kb [bh][z][j][d],
//      VbT [bh][d][m*128+j]
//   3. attention v2 (hazard-ledger HW-validated in r17): block=(bh,z), 512
//      threads, bh=blk&63 (XCD-local). lds_q + lds_p only (50KB -> 3
//      blocks/CU by LDS); V-fragments from global VbT (L2-hot); 2
//      barriers/m. launch_bounds(512,4): natural ~64 VGPR, no spill.
//   4. final GEMM split-K=4, XCD-chunked, swizzled staging, fp16 partials
//      -> k_reduce4 (+bias) -> y (f32)
// Lessons encoded:
//  - r7/r8: do NOT fuse f32->f16 convert into GEMM staging (sync chain).
//  - r9/r10: linear [row][64] LDS tiles = 16-way b128 conflicts; fix =
//    pre-swizzled global source + swizzled read.
//  - r6: 2-barrier attn w/ V-double-buffer failed; cause unknown.
//  - r12/r13: co-residency != overlap; forced interleave is worse.
//  - r14: attn conflicts (3.67M) invariant to lds_p layout (shfl_xor ds-ops).
//  - r15/r16: transpose write-segmentation theory dead; keep 64x64 tiles.
//  - r17: launch_bounds(512,6) forced VGPR 40 -> scratch spill (WRITE_SIZE
//    13->32MB, attn 2x slower). Request only the occupancy you need; let
//    LDS cap occupancy when the natural VGPR count already fits.
// ---------------------------------------------------------------------------

typedef _Float16 h16;
typedef _Float16 h16x4 __attribute__((ext_vector_type(4)));
typedef _Float16 h16x8 __attribute__((ext_vector_type(8)));
typedef float f32x4 __attribute__((ext_vector_type(4)));

#define MFMA16(a, b, c) __builtin_amdgcn_mfma_f32_16x16x32_f16(a, b, c, 0, 0, 0)

// async global->LDS, 16B per lane; lds dest must be wave-uniform base
__device__ __forceinline__ void gload16(const h16* g, h16* l) {
  __builtin_amdgcn_global_load_lds(
      (const __attribute__((address_space(1))) void*)g,
      (__attribute__((address_space(3))) void*)l, 16, 0, 0);
}

// ---------------- prep kernel (x convert + wqkv transpose) ----------------
// blocks [0,2048): x->xh convert; [2048,2112): w_q T; [2112,2240): w_kv T
__global__ __launch_bounds__(256) void k_prep_small(const float* __restrict__ x,
                                                    h16* __restrict__ xh,
                                                    const float* __restrict__ w_q,
                                                    const float* __restrict__ w_kv,
                                                    h16* __restrict__ wqkvT) {
  __shared__ h16 tile[64][68];
  int blk = blockIdx.x, tid = threadIdx.x;
  if (blk < 2048) {  // convert branch (no barrier used)
    int idx = blk * 256 + tid;
    const float4* s4 = (const float4*)x;
    float4 a = s4[idx * 2];
    float4 b = s4[idx * 2 + 1];
    h16x8 o;
    o[0] = (h16)a.x; o[1] = (h16)a.y; o[2] = (h16)a.z; o[3] = (h16)a.w;
    o[4] = (h16)b.x; o[5] = (h16)b.y; o[6] = (h16)b.z; o[7] = (h16)b.w;
    *(h16x8*)&xh[(size_t)idx * 8] = o;
    return;
  }
  const float* src; h16* dst; int R, C, bx, by;
  if (blk < 2112) {
    int b2 = blk - 2048; src = w_q; dst = wqkvT; R = 512; C = 512;
    bx = b2 & 7; by = b2 >> 3;
  } else {
    int b2 = blk - 2112; src = w_kv; dst = wqkvT + 512 * 512; R = 512; C = 1024;
    bx = b2 & 15; by = b2 >> 4;
  }
  int r0 = by * 64, c0 = bx * 64;
  int lr = tid >> 4, lc = (tid & 15) * 4;
#pragma unroll
  for (int s = 0; s < 4; ++s) {
    int r = lr + s * 16;
    float4 v = *(const float4*)&src[(size_t)(r0 + r) * C + c0 + lc];
    h16x4 hq;
    hq[0] = (h16)v.x; hq[1] = (h16)v.y; hq[2] = (h16)v.z; hq[3] = (h16)v.w;
    *(h16x4*)&tile[r][lc] = hq;
  }
  __syncthreads();
  int oc = tid >> 3, os = (tid & 7) * 8;
#pragma unroll
  for (int s = 0; s < 2; ++s) {
    int c = oc + s * 32;
    h16x8 hv;
#pragma unroll
    for (int e = 0; e < 8; ++e) hv[e] = tile[os + e][c];
    *(h16x8*)&dst[(size_t)(c0 + c) * R + r0 + os] = hv;
  }
}

// ------- QKV GEMM + serial-packed w_out transpose (r12 64x64 form) --------
// blk < 768: GEMM A = xh (8192x512 f16), Bt = wqkvT, scatter epilogue.
// blk >= 768: 64x64 transpose tile of w_out (4096x4096 f32) -> woutT f16.
__global__ __launch_bounds__(256, 3) void k_qkv_gemm(const h16* __restrict__ A,
                                                     const h16* __restrict__ Bt,
                                                     const float* __restrict__ w_out,
                                                     h16* __restrict__ Qb,
                                                     h16* __restrict__ Kb,
                                                     h16* __restrict__ VbT,
                                                     h16* __restrict__ woutT) {
  __shared__ __align__(16) h16 As[128 * 64];
  __shared__ __align__(16) h16 Bs[128 * 64];
  int tid = threadIdx.x;

  if (blockIdx.x >= 768) {  // ---- w_out transpose tile (reuses As as LDS) ----
    h16(*tile)[68] = (h16(*)[68])As;
    int b2 = blockIdx.x - 768;
    int bx = b2 & 63, by = b2 >> 6;
    int r0 = by * 64, c0 = bx * 64;
    int lr = tid >> 4, lc = (tid & 15) * 4;
#pragma unroll
    for (int s = 0; s < 4; ++s) {
      int r = lr + s * 16;
      float4 v = *(const float4*)&w_out[(size_t)(r0 + r) * 4096 + c0 + lc];
      h16x4 hq;
      hq[0] = (h16)v.x; hq[1] = (h16)v.y; hq[2] = (h16)v.z; hq[3] = (h16)v.w;
      *(h16x4*)&tile[r][lc] = hq;
    }
    __syncthreads();
    int oc = tid >> 3, os = (tid & 7) * 8;
#pragma unroll
    for (int s = 0; s < 2; ++s) {
      int c = oc + s * 32;
      h16x8 hv;
#pragma unroll
      for (int e = 0; e < 8; ++e) hv[e] = tile[os + e][c];
      *(h16x8*)&woutT[(size_t)(c0 + c) * 4096 + r0 + os] = hv;
    }
    return;
  }

  // ---- GEMM branch: XCD-chunked (XCD k owns tileM [k*8,k*8+8) x 12 tileN) --
  int lg = (blockIdx.x & 7) * 96 + (blockIdx.x >> 3);
  int tileM = lg / 12, tileN = lg % 12;
  int w = tid >> 6, l = tid & 63, g = l >> 4, t = l & 15;
  int wr = w >> 1, wc = w & 1;
  int lr = l >> 3, lch = l & 7;  // staging: row-in-chunk, chunk idx
  const h16* Abase = A + (size_t)(tileM * 128) * 512;
  const h16* Bbase = Bt + (size_t)(tileN * 128) * 512;
  f32x4 acc[4][4];
#pragma unroll
  for (int i = 0; i < 4; ++i)
#pragma unroll
    for (int j = 0; j < 4; ++j) acc[i][j] = (f32x4){0.f, 0.f, 0.f, 0.f};

  for (int k0 = 0; k0 < 512; k0 += 64) {
#pragma unroll
    for (int c = 0; c < 4; ++c) {
      int chunk = w * 4 + c, row = chunk * 8 + lr;
      int sc = (lch ^ (row & 7)) * 8;  // pre-swizzled source chunk
      gload16(Abase + (size_t)row * 512 + k0 + sc, &As[chunk * 512]);
      gload16(Bbase + (size_t)row * 512 + k0 + sc, &Bs[chunk * 512]);
    }
    __syncthreads();
#pragma unroll
    for (int kk = 0; kk < 64; kk += 32) {
      h16x8 af[4], bfr[4];
#pragma unroll
      for (int mi = 0; mi < 4; ++mi) {
        int rr = wr * 64 + mi * 16 + t, c = (kk >> 3) + g;
        af[mi] = *(const h16x8*)&As[rr * 64 + ((c ^ (rr & 7)) << 3)];
      }
#pragma unroll
      for (int ni = 0; ni < 4; ++ni) {
        int rr = wc * 64 + ni * 16 + t, c = (kk >> 3) + g;
        bfr[ni] = *(const h16x8*)&Bs[rr * 64 + ((c ^ (rr & 7)) << 3)];
      }
#pragma unroll
      for (int mi = 0; mi < 4; ++mi)
#pragma unroll
        for (int ni = 0; ni < 4; ++ni) acc[mi][ni] = MFMA16(af[mi], bfr[ni], acc[mi][ni]);
    }
    __syncthreads();
  }
  // scatter epilogue: C<512 -> Q (scaled by log2e/8), C<1024 -> K, else -> V^T
#pragma unroll
  for (int mi = 0; mi < 4; ++mi) {
#pragma unroll
    for (int ni = 0; ni < 4; ++ni) {
      int C = tileN * 128 + wc * 64 + ni * 16 + t;
#pragma unroll
      for (int r = 0; r < 4; ++r) {
        int R = tileM * 128 + wr * 64 + mi * 16 + 4 * g + r;
        float val = acc[mi][ni][r];
        int b = R >> 10, rm = R & 1023;
        int i = rm >> 3, m = rm & 7;
        int bh8 = b * 8;
        if (C < 512) {
          int h = C >> 6, d = C & 63;
          Qb[((size_t)(bh8 + h) * 8 + m) * 8192 + i * 64 + d] = (h16)(val * 0.18033688f);
        } else if (C < 1024) {
          int c2 = C - 512, h = c2 >> 6, d = c2 & 63;
          Kb[((size_t)(bh8 + h) * 1024 + (m * 128 + i)) * 64 + d] = (h16)val;
        } else {
          int c2 = C - 1024, h = c2 >> 6, d = c2 & 63;
          VbT[((size_t)(bh8 + h) * 64 + d) * 1024 + (m * 128 + i)] = (h16)val;
        }
      }
    }
  }
}

// ---------------- attention v2 (512,4): no lds_v, 2 barriers ---------------
// grid 512; bh = blk&63 (same bh -> same XCD-L2), z = blk>>6.
// 512 threads = 8 waves; LDS = 50KB -> 3 blocks/CU (by LDS) at natural
// ~64 VGPR. V-fragments direct from global VbT (L2-hot).
// Hazard ledger validated on HW in r17 (passed, just spilled).
__global__ __launch_bounds__(512, 4) void k_attn(const h16* __restrict__ Qbuf,
                                                 const h16* __restrict__ Kbuf,
                                                 const h16* __restrict__ VbT,
                                                 h16* __restrict__ Ob) {
  __shared__ __align__(16) h16 lds_q[128 * 64];   // Q_m [i][dh], swizzled, 16KB
  __shared__ __align__(16) h16 lds_p[128][136];   // P^T [i][j], padded, 34.8KB
  int blk = blockIdx.x;
  int bh = blk & 63, z = blk >> 6;
  int b = bh >> 3, h = bh & 7;
  const h16* Qb = Qbuf + (size_t)bh * 65536;              // [m][i][d]
  const h16* Kz = Kbuf + (size_t)bh * 65536 + z * 8192;   // [j][d]
  const h16* Vb = VbT + (size_t)bh * 65536;               // [d][u=m*128+j]
  int tid = threadIdx.x, w = tid >> 6, l = tid & 63, g = l >> 4, t = l & 15;

  int qs_r0 = l >> 3, qs_ch = l & 7;    // Q staging: 8 rows/KB, chunk of 8 h16

  // K fragments in registers, loaded ONCE (z-fixed; wave w owns 16 j-rows)
  h16x8 kf[2];
#pragma unroll
  for (int kk = 0; kk < 2; ++kk)
    kf[kk] = *(const h16x8*)&Kz[(w * 16 + t) * 64 + kk * 32 + g * 8];

  f32x4 oa[4];
#pragma unroll
  for (int dt = 0; dt < 4; ++dt) oa[dt] = (f32x4){0.f, 0.f, 0.f, 0.f};

  // prologue: stage Q_0
#pragma unroll
  for (int s = 0; s < 2; ++s) {
    int r = w * 16 + s * 8 + qs_r0;
    gload16(Qb + r * 64 + ((qs_ch ^ (r & 7)) << 3), &lds_q[(w * 16 + s * 8) * 64]);
  }

  for (int m = 0; m < 8; ++m) {
    __syncthreads();  // B1: Q[m] DMA visible; P-write(m) safe vs PV(m-1)

    // T = K_z @ Q_m^T : wave w -> j-rows [w*16,+16) x 128 i-cols
    f32x4 accS[8];
#pragma unroll
    for (int nt = 0; nt < 8; ++nt) accS[nt] = (f32x4){0.f, 0.f, 0.f, 0.f};
#pragma unroll
    for (int kk = 0; kk < 2; ++kk)
#pragma unroll
      for (int nt = 0; nt < 8; ++nt) {
        int rr = nt * 16 + t, c = kk * 4 + g;
        h16x8 bq = *(const h16x8*)&lds_q[rr * 64 + ((c ^ (rr & 7)) << 3)];
        accS[nt] = MFMA16(kf[kk], bq, accS[nt]);
      }

    // softmax over i (cols): in-reg over nt + 16 t-lanes via shfl; no max-sub
    float inv[4];
#pragma unroll
    for (int r = 0; r < 4; ++r) {
      float sum = 0.f;
#pragma unroll
      for (int nt = 0; nt < 8; ++nt) {
        float p = exp2f(accS[nt][r]);
        accS[nt][r] = p;
        sum += p;
      }
#pragma unroll
      for (int msk = 1; msk < 16; msk <<= 1) sum += __shfl_xor(sum, msk);
      inv[r] = 1.f / sum;
    }
    // normalize + cvt + P^T write: lds_p[i = nt*16+t][j = w*16+4g+r]
#pragma unroll
    for (int nt = 0; nt < 8; ++nt) {
      h16x4 pk;
#pragma unroll
      for (int r = 0; r < 4; ++r) pk[r] = (h16)(accS[nt][r] * inv[r]);
      *(h16x4*)&lds_p[nt * 16 + t][w * 16 + 4 * g] = pk;
    }
    __syncthreads();  // B2: lds_p ready; lds_q consumed

    // issue Q[m+1] DMA (drains at B1 of m+1, hidden under PV)
    if (m < 7) {
      const h16* Qm = Qb + (m + 1) * 8192;
#pragma unroll
      for (int s = 0; s < 2; ++s) {
        int r = w * 16 + s * 8 + qs_r0;
        gload16(Qm + r * 64 + ((qs_ch ^ (r & 7)) << 3), &lds_q[(w * 16 + s * 8) * 64]);
      }
    }

    // PV: out[i][d] += sum_j P^T[j][i] * V_m[j][d]; wave w -> i-rows [w*16,+16)
    const h16* Vbm = Vb + m * 128;
#pragma unroll
    for (int kk = 0; kk < 4; ++kk) {
      h16x8 ap = *(const h16x8*)&lds_p[w * 16 + t][kk * 32 + g * 8];
#pragma unroll
      for (int dt = 0; dt < 4; ++dt) {
        h16x8 vf = *(const h16x8*)&Vbm[(size_t)(dt * 16 + t) * 1024 + kk * 32 + g * 8];
        oa[dt] = MFMA16(ap, vf, oa[dt]);
      }
    }
    // no third barrier: next write to lds_p is after B1(m+1)
  }

  // store out_z: Ob[b*128 + i][z*512 + h*64 + d]
#pragma unroll
  for (int dt = 0; dt < 4; ++dt)
#pragma unroll
    for (int r = 0; r < 4; ++r) {
      int i = w * 16 + 4 * g + r;
      Ob[(size_t)(b * 128 + i) * 4096 + z * 512 + h * 64 + dt * 16 + t] = (h16)oa[dt][r];
    }
}

// ---------------- final projection GEMM, split-K=4, swizzled staging ------
// A = Ob (1024x4096), Bt = woutT (4096 x 4096). Grid 1024 = 4 blocks/CU.
// XCD k gets tileN in [k*4, k*4+4) -> per-XCD woutT slice 4MB, L2-resident.
__global__ __launch_bounds__(256, 4) void k_final_gemm(const h16* __restrict__ A,
                                                       const h16* __restrict__ Bt,
                                                       h16* __restrict__ P) {
  __shared__ __align__(16) h16 As[128 * 64];
  __shared__ __align__(16) h16 Bs[128 * 64];
  int tid = threadIdx.x;
  int lg = (blockIdx.x & 7) * 128 + (blockIdx.x >> 3);
  int tileN = lg >> 5;        // [xcd*4, xcd*4+4)
  int rem = lg & 31;
  int tileM = rem >> 2, ks = rem & 3;
  int w = tid >> 6, l = tid & 63, g = l >> 4, t = l & 15;
  int wr = w >> 1, wc = w & 1;
  int lr = l >> 3, lch = l & 7;
  const h16* Abase = A + (size_t)(tileM * 128) * 4096 + ks * 1024;
  const h16* Bbase = Bt + (size_t)(tileN * 128) * 4096 + ks * 1024;
  f32x4 acc[4][4];
#pragma unroll
  for (int i = 0; i < 4; ++i)
#pragma unroll
    for (int j = 0; j < 4; ++j) acc[i][j] = (f32x4){0.f, 0.f, 0.f, 0.f};

  for (int k0 = 0; k0 < 1024; k0 += 64) {
#pragma unroll
    for (int c = 0; c < 4; ++c) {
      int chunk = w * 4 + c, row = chunk * 8 + lr;
      int sc = (lch ^ (row & 7)) * 8;  // pre-swizzled source chunk
      gload16(Abase + (size_t)row * 4096 + k0 + sc, &As[chunk * 512]);
      gload16(Bbase + (size_t)row * 4096 + k0 + sc, &Bs[chunk * 512]);
    }
    __syncthreads();
#pragma unroll
    for (int kk = 0; kk < 64; kk += 32) {
      h16x8 af[4], bfr[4];
#pragma unroll
      for (int mi = 0; mi < 4; ++mi) {
        int rr = wr * 64 + mi * 16 + t, c = (kk >> 3) + g;
        af[mi] = *(const h16x8*)&As[rr * 64 + ((c ^ (rr & 7)) << 3)];
      }
#pragma unroll
      for (int ni = 0; ni < 4; ++ni) {
        int rr = wc * 64 + ni * 16 + t, c = (kk >> 3) + g;
        bfr[ni] = *(const h16x8*)&Bs[rr * 64 + ((c ^ (rr & 7)) << 3)];
      }
#pragma unroll
      for (int mi = 0; mi < 4; ++mi)
#pragma unroll
        for (int ni = 0; ni < 4; ++ni) acc[mi][ni] = MFMA16(af[mi], bfr[ni], acc[mi][ni]);
    }
    __syncthreads();
  }
  h16* Pk = P + (size_t)ks * 4194304;
#pragma unroll
  for (int mi = 0; mi < 4; ++mi) {
#pragma unroll
    for (int ni = 0; ni < 4; ++ni) {
      int C = tileN * 128 + wc * 64 + ni * 16 + t;
#pragma unroll
      for (int r = 0; r < 4; ++r) {
        int R = tileM * 128 + wr * 64 + mi * 16 + 4 * g + r;
        Pk[(size_t)R * 4096 + C] = (h16)acc[mi][ni][r];
      }
    }
  }
}

// y = p0+p1+p2+p3 + bias; 8 elems/thread, grid 2048
__global__ __launch_bounds__(256) void k_reduce4(const h16* __restrict__ P,
                                                 const float* __restrict__ bias,
                                                 float* __restrict__ Y) {
  int idx = blockIdx.x * 256 + threadIdx.x;
  size_t base = (size_t)idx * 8;
  h16x8 p0 = *(const h16x8*)&P[base];
  h16x8 p1 = *(const h16x8*)&P[base + 4194304];
  h16x8 p2 = *(const h16x8*)&P[base + 8388608];
  h16x8 p3 = *(const h16x8*)&P[base + 12582912];
  int cb = (int)(base & 4095);
  float4 b0 = *(const float4*)&bias[cb];
  float4 b1 = *(const float4*)&bias[cb + 4];
  float4 o0, o1;
  o0.x = (float)p0[0] + (float)p1[0] + (float)p2[0] + (float)p3[0] + b0.x;
  o0.y = (float)p0[1] + (float)p1[1] + (float)p2[1] + (float)p3[1] + b0.y;
  o0.z = (float)p0[2] + (float)p1[2] + (float)p2[2] + (float)p3[2] + b0.z;
  o0.w = (float)p0[3] + (float)p1[3] + (float)p2[3] + (float)p3[3] + b0.w;
  o1.x = (float)p0[4] + (float)p1[4] + (float)p2[4] + (float)p3[4] + b1.x;
  o1.y = (float)p0[5] + (float)p1[5] + (float)p2[5] + (float)p3[5] + b1.y;
  o1.z = (float)p0[6] + (float)p1[6] + (float)p2[6] + (float)p3[6] + b1.z;
  o1.w = (float)p0[7] + (float)p1[7] + (float)p2[7] + (float)p3[7] + b1.w;
  *(float4*)&Y[base] = o0;
  *(float4*)&Y[base + 4] = o1;
}

// ---------------- launch ----------------

extern "C" void kernel_launch(void* const* d_in, const int* in_sizes, int n_in,
                              void* d_out, int out_size, void* d_ws, size_t ws_size,
                              hipStream_t stream) {
  const float* x = (const float*)d_in[0];
  const float* w_q = (const float*)d_in[1];
  const float* w_kv = (const float*)d_in[2];
  const float* w_out = (const float*)d_in[3];
  const float* b_out = (const float*)d_in[4];
  float* y = (float*)d_out;

  char* ws = (char*)d_ws;
  h16* woutT = (h16*)(ws + 0);          // 32 MB  (alive to the end)
  h16* Ob    = (h16*)(ws + 33554432);   //  8 MB  (alive to the end)
  h16* xh    = (h16*)(ws + 41943040);   //  8 MB  (dead after qkv)
  h16* wqkvT = (h16*)(ws + 50331648);   //  1.5MB (dead after qkv)
  h16* Qb    = (h16*)(ws + 51904512);   //  8 MB  (dead after attn)
  h16* Kb    = (h16*)(ws + 60293120);   //  8 MB  (dead after attn)
  h16* VbT   = (h16*)(ws + 68681728);   //  8 MB  (dead after attn)
  h16* Pp    = (h16*)(ws + 41943040);   // 32 MB partials, overlays dead region
  (void)ws_size; (void)in_sizes; (void)n_in; (void)out_size;

  k_prep_small<<<dim3(2240), dim3(256), 0, stream>>>(x, xh, w_q, w_kv, wqkvT);
  k_qkv_gemm<<<dim3(4864), dim3(256), 0, stream>>>(xh, wqkvT, w_out, Qb, Kb, VbT, woutT);
  k_attn<<<dim3(512), dim3(512), 0, stream>>>(Qb, Kb, VbT, Ob);
  k_final_gemm<<<dim3(1024), dim3(256), 0, stream>>>(Ob, woutT, Pp);
  k_reduce4<<<dim3(2048), dim3(256), 0, stream>>>(Pp, b_out, y);
}

// Round 19
// 145.982 us; speedup vs baseline: 1.3162x; 1.2270x over previous
//
#include <hip/hip_runtime.h>

// ---------------------------------------------------------------------------
// Channel_Seq_Big_Attention: B=8,N=128,M=8,D=512,H=8,DH=64, INNER=512
// Softmax is over axis=2 of (b,h,i,j,m,z) == QUERY seq axis i.
// Pipeline (fp16 compute, fp32 accumulate)  [r12 configuration, best=146.0us]:
//   1. k_prep_small: x->xh f16 | w_q,w_kv -> wqkvT [n][k] (vectorized).
//   2. k_qkv_gemm (merged launch, serial-packed): blk<768 = QKV GEMM (async
//      swizzled staging, XCD-chunked); blk>=768 = w_out transpose tiles
//      (64x64). Scatter: Qb [bh][m][i][d] (log2e/8), Kb [bh][z][j][d],
//      VbT [bh][d][m*128+j]
//   3. attention (r5 structure): block=(bh,z), 512 threads, bh=blk&63
//      (XCD-local). 3-barrier m-loop, lds_q+lds_v+padded lds_p, K in regs.
//   4. final GEMM split-K=4, XCD-chunked, swizzled staging, fp16 partials
//      -> k_reduce4 (+bias) -> y (f32)
// Lesson ledger (all falsified alternatives, do not re-roll):
//  - r7/r8: do NOT fuse f32->f16 convert into GEMM staging (sync chain
//    displaces global_load_lds; ~25us latency).
//  - r9/r10: linear [row][64] LDS tiles = 16-way b128 conflicts; fix =
//    pre-swizzled global source + swizzled read (12.6M cycles -> ~0).
//  - r6: 2-barrier attn w/ V-double-buffer failed correctness; cause never
//    isolated.
//  - r12/r13: co-residency != overlap; forced interleave overlap is WORSE
//    (background BW lengthens the latency-bound kernel's L2 critical path).
//  - r14: attn's 3.67M conflict cycles invariant to lds_p layout; source is
//    the shfl_xor softmax ds-ops, not tile reads.
//  - r15/r16: transpose write-segmentation theory dead (256x32 tiles slower
//    than 64x64 even conflict-free).
//  - r17: over-tight launch_bounds forces VGPR spill (WRITE_SIZE 13->32MB).
//  - r18: direct-global V-fragments (no lds_v) = 80us attn even w/o spill:
//    per-MFMA L2 latency on critical path + 8x redundant per-wave V reads.
//    lds_v staging is structurally required.
// ---------------------------------------------------------------------------

typedef _Float16 h16;
typedef _Float16 h16x4 __attribute__((ext_vector_type(4)));
typedef _Float16 h16x8 __attribute__((ext_vector_type(8)));
typedef float f32x4 __attribute__((ext_vector_type(4)));

#define MFMA16(a, b, c) __builtin_amdgcn_mfma_f32_16x16x32_f16(a, b, c, 0, 0, 0)

// async global->LDS, 16B per lane; lds dest must be wave-uniform base
__device__ __forceinline__ void gload16(const h16* g, h16* l) {
  __builtin_amdgcn_global_load_lds(
      (const __attribute__((address_space(1))) void*)g,
      (__attribute__((address_space(3))) void*)l, 16, 0, 0);
}

// ---------------- prep kernel (x convert + wqkv transpose) ----------------
// blocks [0,2048): x->xh convert; [2048,2112): w_q T; [2112,2240): w_kv T
__global__ __launch_bounds__(256) void k_prep_small(const float* __restrict__ x,
                                                    h16* __restrict__ xh,
                                                    const float* __restrict__ w_q,
                                                    const float* __restrict__ w_kv,
                                                    h16* __restrict__ wqkvT) {
  __shared__ h16 tile[64][68];
  int blk = blockIdx.x, tid = threadIdx.x;
  if (blk < 2048) {  // convert branch (no barrier used)
    int idx = blk * 256 + tid;
    const float4* s4 = (const float4*)x;
    float4 a = s4[idx * 2];
    float4 b = s4[idx * 2 + 1];
    h16x8 o;
    o[0] = (h16)a.x; o[1] = (h16)a.y; o[2] = (h16)a.z; o[3] = (h16)a.w;
    o[4] = (h16)b.x; o[5] = (h16)b.y; o[6] = (h16)b.z; o[7] = (h16)b.w;
    *(h16x8*)&xh[(size_t)idx * 8] = o;
    return;
  }
  const float* src; h16* dst; int R, C, bx, by;
  if (blk < 2112) {
    int b2 = blk - 2048; src = w_q; dst = wqkvT; R = 512; C = 512;
    bx = b2 & 7; by = b2 >> 3;
  } else {
    int b2 = blk - 2112; src = w_kv; dst = wqkvT + 512 * 512; R = 512; C = 1024;
    bx = b2 & 15; by = b2 >> 4;
  }
  int r0 = by * 64, c0 = bx * 64;
  int lr = tid >> 4, lc = (tid & 15) * 4;
#pragma unroll
  for (int s = 0; s < 4; ++s) {
    int r = lr + s * 16;
    float4 v = *(const float4*)&src[(size_t)(r0 + r) * C + c0 + lc];
    h16x4 hq;
    hq[0] = (h16)v.x; hq[1] = (h16)v.y; hq[2] = (h16)v.z; hq[3] = (h16)v.w;
    *(h16x4*)&tile[r][lc] = hq;
  }
  __syncthreads();
  int oc = tid >> 3, os = (tid & 7) * 8;
#pragma unroll
  for (int s = 0; s < 2; ++s) {
    int c = oc + s * 32;
    h16x8 hv;
#pragma unroll
    for (int e = 0; e < 8; ++e) hv[e] = tile[os + e][c];
    *(h16x8*)&dst[(size_t)(c0 + c) * R + r0 + os] = hv;
  }
}

// ------- QKV GEMM + serial-packed w_out transpose (r12 form) --------------
// blk < 768: GEMM A = xh (8192x512 f16), Bt = wqkvT, scatter epilogue.
// blk >= 768: 64x64 transpose tile of w_out (4096x4096 f32) -> woutT f16.
__global__ __launch_bounds__(256, 3) void k_qkv_gemm(const h16* __restrict__ A,
                                                     const h16* __restrict__ Bt,
                                                     const float* __restrict__ w_out,
                                                     h16* __restrict__ Qb,
                                                     h16* __restrict__ Kb,
                                                     h16* __restrict__ VbT,
                                                     h16* __restrict__ woutT) {
  __shared__ __align__(16) h16 As[128 * 64];
  __shared__ __align__(16) h16 Bs[128 * 64];
  int tid = threadIdx.x;

  if (blockIdx.x >= 768) {  // ---- w_out transpose tile (reuses As as LDS) ----
    h16(*tile)[68] = (h16(*)[68])As;
    int b2 = blockIdx.x - 768;
    int bx = b2 & 63, by = b2 >> 6;
    int r0 = by * 64, c0 = bx * 64;
    int lr = tid >> 4, lc = (tid & 15) * 4;
#pragma unroll
    for (int s = 0; s < 4; ++s) {
      int r = lr + s * 16;
      float4 v = *(const float4*)&w_out[(size_t)(r0 + r) * 4096 + c0 + lc];
      h16x4 hq;
      hq[0] = (h16)v.x; hq[1] = (h16)v.y; hq[2] = (h16)v.z; hq[3] = (h16)v.w;
      *(h16x4*)&tile[r][lc] = hq;
    }
    __syncthreads();
    int oc = tid >> 3, os = (tid & 7) * 8;
#pragma unroll
    for (int s = 0; s < 2; ++s) {
      int c = oc + s * 32;
      h16x8 hv;
#pragma unroll
      for (int e = 0; e < 8; ++e) hv[e] = tile[os + e][c];
      *(h16x8*)&woutT[(size_t)(c0 + c) * 4096 + r0 + os] = hv;
    }
    return;
  }

  // ---- GEMM branch: XCD-chunked (XCD k owns tileM [k*8,k*8+8) x 12 tileN) --
  int lg = (blockIdx.x & 7) * 96 + (blockIdx.x >> 3);
  int tileM = lg / 12, tileN = lg % 12;
  int w = tid >> 6, l = tid & 63, g = l >> 4, t = l & 15;
  int wr = w >> 1, wc = w & 1;
  int lr = l >> 3, lch = l & 7;  // staging: row-in-chunk, chunk idx
  const h16* Abase = A + (size_t)(tileM * 128) * 512;
  const h16* Bbase = Bt + (size_t)(tileN * 128) * 512;
  f32x4 acc[4][4];
#pragma unroll
  for (int i = 0; i < 4; ++i)
#pragma unroll
    for (int j = 0; j < 4; ++j) acc[i][j] = (f32x4){0.f, 0.f, 0.f, 0.f};

  for (int k0 = 0; k0 < 512; k0 += 64) {
#pragma unroll
    for (int c = 0; c < 4; ++c) {
      int chunk = w * 4 + c, row = chunk * 8 + lr;
      int sc = (lch ^ (row & 7)) * 8;  // pre-swizzled source chunk
      gload16(Abase + (size_t)row * 512 + k0 + sc, &As[chunk * 512]);
      gload16(Bbase + (size_t)row * 512 + k0 + sc, &Bs[chunk * 512]);
    }
    __syncthreads();
#pragma unroll
    for (int kk = 0; kk < 64; kk += 32) {
      h16x8 af[4], bfr[4];
#pragma unroll
      for (int mi = 0; mi < 4; ++mi) {
        int rr = wr * 64 + mi * 16 + t, c = (kk >> 3) + g;
        af[mi] = *(const h16x8*)&As[rr * 64 + ((c ^ (rr & 7)) << 3)];
      }
#pragma unroll
      for (int ni = 0; ni < 4; ++ni) {
        int rr = wc * 64 + ni * 16 + t, c = (kk >> 3) + g;
        bfr[ni] = *(const h16x8*)&Bs[rr * 64 + ((c ^ (rr & 7)) << 3)];
      }
#pragma unroll
      for (int mi = 0; mi < 4; ++mi)
#pragma unroll
        for (int ni = 0; ni < 4; ++ni) acc[mi][ni] = MFMA16(af[mi], bfr[ni], acc[mi][ni]);
    }
    __syncthreads();
  }
  // scatter epilogue: C<512 -> Q (scaled by log2e/8), C<1024 -> K, else -> V^T
#pragma unroll
  for (int mi = 0; mi < 4; ++mi) {
#pragma unroll
    for (int ni = 0; ni < 4; ++ni) {
      int C = tileN * 128 + wc * 64 + ni * 16 + t;
#pragma unroll
      for (int r = 0; r < 4; ++r) {
        int R = tileM * 128 + wr * 64 + mi * 16 + 4 * g + r;
        float val = acc[mi][ni][r];
        int b = R >> 10, rm = R & 1023;
        int i = rm >> 3, m = rm & 7;
        int bh8 = b * 8;
        if (C < 512) {
          int h = C >> 6, d = C & 63;
          Qb[((size_t)(bh8 + h) * 8 + m) * 8192 + i * 64 + d] = (h16)(val * 0.18033688f);
        } else if (C < 1024) {
          int c2 = C - 512, h = c2 >> 6, d = c2 & 63;
          Kb[((size_t)(bh8 + h) * 1024 + (m * 128 + i)) * 64 + d] = (h16)val;
        } else {
          int c2 = C - 1024, h = c2 >> 6, d = c2 & 63;
          VbT[((size_t)(bh8 + h) * 64 + d) * 1024 + (m * 128 + i)] = (h16)val;
        }
      }
    }
  }
}

// ---------------- attention (r5 structure, known-best 49.2us) --------------
// grid 512; bh = blk&63 (same bh -> same XCD-L2), z = blk>>6.
// 512 threads = 8 waves -> 16 waves/CU at 2 blocks/CU.
__global__ __launch_bounds__(512, 4) void k_attn(const h16* __restrict__ Qbuf,
                                                 const h16* __restrict__ Kbuf,
                                                 const h16* __restrict__ VbT,
                                                 h16* __restrict__ Ob) {
  __shared__ __align__(16) h16 lds_q[128 * 64];   // Q_m [i][dh], swizzled, 16KB
  __shared__ __align__(16) h16 lds_v[64 * 128];   // V_m [d][j], swizzled, 16KB
  __shared__ __align__(16) h16 lds_p[128][136];   // P^T [i][j], padded, 34.8KB
  int blk = blockIdx.x;
  int bh = blk & 63, z = blk >> 6;
  int b = bh >> 3, h = bh & 7;
  const h16* Qb = Qbuf + (size_t)bh * 65536;              // [m][i][d]
  const h16* Kz = Kbuf + (size_t)bh * 65536 + z * 8192;   // [j][d]
  const h16* Vb = VbT + (size_t)bh * 65536;               // [d][u=m*128+j]
  int tid = threadIdx.x, w = tid >> 6, l = tid & 63, g = l >> 4, t = l & 15;

  int qs_r0 = l >> 3, qs_ch = l & 7;    // Q: 8 rows/KB, chunk of 8 h16
  int vs_r0 = l >> 4, vs_ch = l & 15;   // V: 4 rows/KB, chunk of 8 h16

  // K fragments in registers, loaded ONCE (z-fixed; wave w owns 16 j-rows)
  h16x8 kf[2];
#pragma unroll
  for (int kk = 0; kk < 2; ++kk)
    kf[kk] = *(const h16x8*)&Kz[(w * 16 + t) * 64 + kk * 32 + g * 8];

  f32x4 oa[4];
#pragma unroll
  for (int dt = 0; dt < 4; ++dt) oa[dt] = (f32x4){0.f, 0.f, 0.f, 0.f};

  // prologue: stage Q_0 and V_0
  {
    const h16* Qm = Qb;
#pragma unroll
    for (int s = 0; s < 2; ++s) {
      int r = w * 16 + s * 8 + qs_r0;
      gload16(Qm + r * 64 + ((qs_ch ^ (r & 7)) << 3), &lds_q[(w * 16 + s * 8) * 64]);
    }
#pragma unroll
    for (int s = 0; s < 2; ++s) {
      int r = w * 8 + s * 4 + vs_r0;
      gload16(Vb + (size_t)r * 1024 + ((vs_ch ^ (r & 7)) << 3), &lds_v[(w * 8 + s * 4) * 128]);
    }
  }

  for (int m = 0; m < 8; ++m) {
    __syncthreads();  // staged Q_m/V_m visible (barrier drains DMA vmcnt)

    // T = K_z @ Q_m^T : wave w -> j-rows [w*16,+16) x 128 i-cols
    f32x4 accS[8];
#pragma unroll
    for (int nt = 0; nt < 8; ++nt) accS[nt] = (f32x4){0.f, 0.f, 0.f, 0.f};
#pragma unroll
    for (int kk = 0; kk < 2; ++kk)
#pragma unroll
      for (int nt = 0; nt < 8; ++nt) {
        int rr = nt * 16 + t, c = kk * 4 + g;
        h16x8 bq = *(const h16x8*)&lds_q[rr * 64 + ((c ^ (rr & 7)) << 3)];
        accS[nt] = MFMA16(kf[kk], bq, accS[nt]);
      }

    // softmax over i (cols): in-reg over nt + 16 t-lanes via shfl; no max-sub
    float inv[4];
#pragma unroll
    for (int r = 0; r < 4; ++r) {
      float sum = 0.f;
#pragma unroll
      for (int nt = 0; nt < 8; ++nt) {
        float p = exp2f(accS[nt][r]);
        accS[nt][r] = p;
        sum += p;
      }
#pragma unroll
      for (int msk = 1; msk < 16; msk <<= 1) sum += __shfl_xor(sum, msk);
      inv[r] = 1.f / sum;
    }
    // normalize + cvt + P^T write: lds_p[i = nt*16+t][j = w*16+4g+r]
#pragma unroll
    for (int nt = 0; nt < 8; ++nt) {
      h16x4 pk;
#pragma unroll
      for (int r = 0; r < 4; ++r) pk[r] = (h16)(accS[nt][r] * inv[r]);
      *(h16x4*)&lds_p[nt * 16 + t][w * 16 + 4 * g] = pk;
    }
    __syncthreads();  // lds_p ready; lds_q free

    // overlap: stage Q_{m+1} into lds_q while PV computes
    if (m < 7) {
      const h16* Qm = Qb + (m + 1) * 8192;
#pragma unroll
      for (int s = 0; s < 2; ++s) {
        int r = w * 16 + s * 8 + qs_r0;
        gload16(Qm + r * 64 + ((qs_ch ^ (r & 7)) << 3), &lds_q[(w * 16 + s * 8) * 64]);
      }
    }

    // PV: out[i][d] += sum_j P^T[j][i] * V_m[j][d]; wave w -> i-rows [w*16,+16)
#pragma unroll
    for (int kk = 0; kk < 4; ++kk) {
      h16x8 ap = *(const h16x8*)&lds_p[w * 16 + t][kk * 32 + g * 8];
#pragma unroll
      for (int dt = 0; dt < 4; ++dt) {
        int rr = dt * 16 + t, c = kk * 4 + g;
        h16x8 vf = *(const h16x8*)&lds_v[rr * 128 + ((c ^ (rr & 7)) << 3)];
        oa[dt] = MFMA16(ap, vf, oa[dt]);
      }
    }
    __syncthreads();  // all PV reads of lds_v/lds_p done

    if (m < 7) {
      const h16* Vm = Vb + (m + 1) * 128;
#pragma unroll
      for (int s = 0; s < 2; ++s) {
        int r = w * 8 + s * 4 + vs_r0;
        gload16(Vm + (size_t)r * 1024 + ((vs_ch ^ (r & 7)) << 3), &lds_v[(w * 8 + s * 4) * 128]);
      }
    }
  }

  // store out_z: Ob[b*128 + i][z*512 + h*64 + d]
#pragma unroll
  for (int dt = 0; dt < 4; ++dt)
#pragma unroll
    for (int r = 0; r < 4; ++r) {
      int i = w * 16 + 4 * g + r;
      Ob[(size_t)(b * 128 + i) * 4096 + z * 512 + h * 64 + dt * 16 + t] = (h16)oa[dt][r];
    }
}

// ---------------- final projection GEMM, split-K=4, swizzled staging ------
// A = Ob (1024x4096), Bt = woutT (4096 x 4096). Grid 1024 = 4 blocks/CU.
// XCD k gets tileN in [k*4, k*4+4) -> per-XCD woutT slice 4MB, L2-resident.
__global__ __launch_bounds__(256, 4) void k_final_gemm(const h16* __restrict__ A,
                                                       const h16* __restrict__ Bt,
                                                       h16* __restrict__ P) {
  __shared__ __align__(16) h16 As[128 * 64];
  __shared__ __align__(16) h16 Bs[128 * 64];
  int tid = threadIdx.x;
  int lg = (blockIdx.x & 7) * 128 + (blockIdx.x >> 3);
  int tileN = lg >> 5;        // [xcd*4, xcd*4+4)
  int rem = lg & 31;
  int tileM = rem >> 2, ks = rem & 3;
  int w = tid >> 6, l = tid & 63, g = l >> 4, t = l & 15;
  int wr = w >> 1, wc = w & 1;
  int lr = l >> 3, lch = l & 7;
  const h16* Abase = A + (size_t)(tileM * 128) * 4096 + ks * 1024;
  const h16* Bbase = Bt + (size_t)(tileN * 128) * 4096 + ks * 1024;
  f32x4 acc[4][4];
#pragma unroll
  for (int i = 0; i < 4; ++i)
#pragma unroll
    for (int j = 0; j < 4; ++j) acc[i][j] = (f32x4){0.f, 0.f, 0.f, 0.f};

  for (int k0 = 0; k0 < 1024; k0 += 64) {
#pragma unroll
    for (int c = 0; c < 4; ++c) {
      int chunk = w * 4 + c, row = chunk * 8 + lr;
      int sc = (lch ^ (row & 7)) * 8;  // pre-swizzled source chunk
      gload16(Abase + (size_t)row * 4096 + k0 + sc, &As[chunk * 512]);
      gload16(Bbase + (size_t)row * 4096 + k0 + sc, &Bs[chunk * 512]);
    }
    __syncthreads();
#pragma unroll
    for (int kk = 0; kk < 64; kk += 32) {
      h16x8 af[4], bfr[4];
#pragma unroll
      for (int mi = 0; mi < 4; ++mi) {
        int rr = wr * 64 + mi * 16 + t, c = (kk >> 3) + g;
        af[mi] = *(const h16x8*)&As[rr * 64 + ((c ^ (rr & 7)) << 3)];
      }
#pragma unroll
      for (int ni = 0; ni < 4; ++ni) {
        int rr = wc * 64 + ni * 16 + t, c = (kk >> 3) + g;
        bfr[ni] = *(const h16x8*)&Bs[rr * 64 + ((c ^ (rr & 7)) << 3)];
      }
#pragma unroll
      for (int mi = 0; mi < 4; ++mi)
#pragma unroll
        for (int ni = 0; ni < 4; ++ni) acc[mi][ni] = MFMA16(af[mi], bfr[ni], acc[mi][ni]);
    }
    __syncthreads();
  }
  h16* Pk = P + (size_t)ks * 4194304;
#pragma unroll
  for (int mi = 0; mi < 4; ++mi) {
#pragma unroll
    for (int ni = 0; ni < 4; ++ni) {
      int C = tileN * 128 + wc * 64 + ni * 16 + t;
#pragma unroll
      for (int r = 0; r < 4; ++r) {
        int R = tileM * 128 + wr * 64 + mi * 16 + 4 * g + r;
        Pk[(size_t)R * 4096 + C] = (h16)acc[mi][ni][r];
      }
    }
  }
}

// y = p0+p1+p2+p3 + bias; 8 elems/thread, grid 2048
__global__ __launch_bounds__(256) void k_reduce4(const h16* __restrict__ P,
                                                 const float* __restrict__ bias,
                                                 float* __restrict__ Y) {
  int idx = blockIdx.x * 256 + threadIdx.x;
  size_t base = (size_t)idx * 8;
  h16x8 p0 = *(const h16x8*)&P[base];
  h16x8 p1 = *(const h16x8*)&P[base + 4194304];
  h16x8 p2 = *(const h16x8*)&P[base + 8388608];
  h16x8 p3 = *(const h16x8*)&P[base + 12582912];
  int cb = (int)(base & 4095);
  float4 b0 = *(const float4*)&bias[cb];
  float4 b1 = *(const float4*)&bias[cb + 4];
  float4 o0, o1;
  o0.x = (float)p0[0] + (float)p1[0] + (float)p2[0] + (float)p3[0] + b0.x;
  o0.y = (float)p0[1] + (float)p1[1] + (float)p2[1] + (float)p3[1] + b0.y;
  o0.z = (float)p0[2] + (float)p1[2] + (float)p2[2] + (float)p3[2] + b0.z;
  o0.w = (float)p0[3] + (float)p1[3] + (float)p2[3] + (float)p3[3] + b0.w;
  o1.x = (float)p0[4] + (float)p1[4] + (float)p2[4] + (float)p3[4] + b1.x;
  o1.y = (float)p0[5] + (float)p1[5] + (float)p2[5] + (float)p3[5] + b1.y;
  o1.z = (float)p0[6] + (float)p1[6] + (float)p2[6] + (float)p3[6] + b1.z;
  o1.w = (float)p0[7] + (float)p1[7] + (float)p2[7] + (float)p3[7] + b1.w;
  *(float4*)&Y[base] = o0;
  *(float4*)&Y[base + 4] = o1;
}

// ---------------- launch ----------------

extern "C" void kernel_launch(void* const* d_in, const int* in_sizes, int n_in,
                              void* d_out, int out_size, void* d_ws, size_t ws_size,
                              hipStream_t stream) {
  const float* x = (const float*)d_in[0];
  const float* w_q = (const float*)d_in[1];
  const float* w_kv = (const float*)d_in[2];
  const float* w_out = (const float*)d_in[3];
  const float* b_out = (const float*)d_in[4];
  float* y = (float*)d_out;

  char* ws = (char*)d_ws;
  h16* woutT = (h16*)(ws + 0);          // 32 MB  (alive to the end)
  h16* Ob    = (h16*)(ws + 33554432);   //  8 MB  (alive to the end)
  h16* xh    = (h16*)(ws + 41943040);   //  8 MB  (dead after qkv)
  h16* wqkvT = (h16*)(ws + 50331648);   //  1.5MB (dead after qkv)
  h16* Qb    = (h16*)(ws + 51904512);   //  8 MB  (dead after attn)
  h16* Kb    = (h16*)(ws + 60293120);   //  8 MB  (dead after attn)
  h16* VbT   = (h16*)(ws + 68681728);   //  8 MB  (dead after attn)
  h16* Pp    = (h16*)(ws + 41943040);   // 32 MB partials, overlays dead region
  (void)ws_size; (void)in_sizes; (void)n_in; (void)out_size;

  k_prep_small<<<dim3(2240), dim3(256), 0, stream>>>(x, xh, w_q, w_kv, wqkvT);
  k_qkv_gemm<<<dim3(4864), dim3(256), 0, stream>>>(xh, wqkvT, w_out, Qb, Kb, VbT, woutT);
  k_attn<<<dim3(512), dim3(512), 0, stream>>>(Qb, Kb, VbT, Ob);
  k_final_gemm<<<dim3(1024), dim3(256), 0, stream>>>(Ob, woutT, Pp);
  k_reduce4<<<dim3(2048), dim3(256), 0, stream>>>(Pp, b_out, y);
}

// Round 20
// 145.155 us; speedup vs baseline: 1.3236x; 1.0057x over previous
//
#include <hip/hip_runtime.h>

// ---------------------------------------------------------------------------
// Channel_Seq_Big_Attention: B=8,N=128,M=8,D=512,H=8,DH=64, INNER=512
// Softmax is over axis=2 of (b,h,i,j,m,z) == QUERY seq axis i.
// Pipeline (fp16 compute, fp32 accumulate)  [r12 config + r20 barrier-elide]:
//   1. k_prep_small: x->xh f16 | w_q,w_kv -> wqkvT [n][k] (vectorized).
//   2. k_qkv_gemm (merged launch, serial-packed): blk<768 = QKV GEMM (async
//      swizzled staging, XCD-chunked); blk>=768 = w_out transpose tiles
//      (64x64). Scatter: Qb [bh][m][i][d] (log2e/8), Kb [bh][z][j][d],
//      VbT [bh][d][m*128+j]
//   3. attention (r5 structure, 2 in-loop barriers): block=(bh,z), 512
//      threads, bh=blk&63 (XCD-local). Loop-top barrier proven redundant
//      (ledger: Q-DMA drained by B3; P-write ordered by B3; V-DMA drained
//      by B2) -> single prologue barrier + B2/B3 per m.
//   4. final GEMM split-K=4, XCD-chunked, swizzled staging, fp16 partials
//      -> k_reduce4 (+bias) -> y (f32)
// Lesson ledger (falsified alternatives, do not re-roll):
//  - r7/r8: do NOT fuse f32->f16 convert into GEMM staging (sync chain).
//  - r9/r10: linear [row][64] LDS tiles = 16-way b128 conflicts; fix =
//    pre-swizzled global source + swizzled read.
//  - r6: 2-barrier attn w/ V-DOUBLE-BUFFER failed correctness (this r20
//    elide is single-buffer, different hazard structure, ledger-verified).
//  - r12/r13: co-residency != overlap; forced interleave overlap is worse.
//  - r14: attn conflicts invariant to lds_p layout (shfl_xor ds-ops).
//  - r15/r16: transpose write-segmentation theory dead; keep 64x64 tiles.
//  - r17: over-tight launch_bounds -> VGPR spill (WRITE_SIZE 13->32MB).
//  - r18: no-lds_v attn = 80us (per-MFMA L2 latency + 8x redundant V reads).
// ---------------------------------------------------------------------------

typedef _Float16 h16;
typedef _Float16 h16x4 __attribute__((ext_vector_type(4)));
typedef _Float16 h16x8 __attribute__((ext_vector_type(8)));
typedef float f32x4 __attribute__((ext_vector_type(4)));

#define MFMA16(a, b, c) __builtin_amdgcn_mfma_f32_16x16x32_f16(a, b, c, 0, 0, 0)

// async global->LDS, 16B per lane; lds dest must be wave-uniform base
__device__ __forceinline__ void gload16(const h16* g, h16* l) {
  __builtin_amdgcn_global_load_lds(
      (const __attribute__((address_space(1))) void*)g,
      (__attribute__((address_space(3))) void*)l, 16, 0, 0);
}

// ---------------- prep kernel (x convert + wqkv transpose) ----------------
// blocks [0,2048): x->xh convert; [2048,2112): w_q T; [2112,2240): w_kv T
__global__ __launch_bounds__(256) void k_prep_small(const float* __restrict__ x,
                                                    h16* __restrict__ xh,
                                                    const float* __restrict__ w_q,
                                                    const float* __restrict__ w_kv,
                                                    h16* __restrict__ wqkvT) {
  __shared__ h16 tile[64][68];
  int blk = blockIdx.x, tid = threadIdx.x;
  if (blk < 2048) {  // convert branch (no barrier used)
    int idx = blk * 256 + tid;
    const float4* s4 = (const float4*)x;
    float4 a = s4[idx * 2];
    float4 b = s4[idx * 2 + 1];
    h16x8 o;
    o[0] = (h16)a.x; o[1] = (h16)a.y; o[2] = (h16)a.z; o[3] = (h16)a.w;
    o[4] = (h16)b.x; o[5] = (h16)b.y; o[6] = (h16)b.z; o[7] = (h16)b.w;
    *(h16x8*)&xh[(size_t)idx * 8] = o;
    return;
  }
  const float* src; h16* dst; int R, C, bx, by;
  if (blk < 2112) {
    int b2 = blk - 2048; src = w_q; dst = wqkvT; R = 512; C = 512;
    bx = b2 & 7; by = b2 >> 3;
  } else {
    int b2 = blk - 2112; src = w_kv; dst = wqkvT + 512 * 512; R = 512; C = 1024;
    bx = b2 & 15; by = b2 >> 4;
  }
  int r0 = by * 64, c0 = bx * 64;
  int lr = tid >> 4, lc = (tid & 15) * 4;
#pragma unroll
  for (int s = 0; s < 4; ++s) {
    int r = lr + s * 16;
    float4 v = *(const float4*)&src[(size_t)(r0 + r) * C + c0 + lc];
    h16x4 hq;
    hq[0] = (h16)v.x; hq[1] = (h16)v.y; hq[2] = (h16)v.z; hq[3] = (h16)v.w;
    *(h16x4*)&tile[r][lc] = hq;
  }
  __syncthreads();
  int oc = tid >> 3, os = (tid & 7) * 8;
#pragma unroll
  for (int s = 0; s < 2; ++s) {
    int c = oc + s * 32;
    h16x8 hv;
#pragma unroll
    for (int e = 0; e < 8; ++e) hv[e] = tile[os + e][c];
    *(h16x8*)&dst[(size_t)(c0 + c) * R + r0 + os] = hv;
  }
}

// ------- QKV GEMM + serial-packed w_out transpose (r12 form) --------------
// blk < 768: GEMM A = xh (8192x512 f16), Bt = wqkvT, scatter epilogue.
// blk >= 768: 64x64 transpose tile of w_out (4096x4096 f32) -> woutT f16.
__global__ __launch_bounds__(256, 3) void k_qkv_gemm(const h16* __restrict__ A,
                                                     const h16* __restrict__ Bt,
                                                     const float* __restrict__ w_out,
                                                     h16* __restrict__ Qb,
                                                     h16* __restrict__ Kb,
                                                     h16* __restrict__ VbT,
                                                     h16* __restrict__ woutT) {
  __shared__ __align__(16) h16 As[128 * 64];
  __shared__ __align__(16) h16 Bs[128 * 64];
  int tid = threadIdx.x;

  if (blockIdx.x >= 768) {  // ---- w_out transpose tile (reuses As as LDS) ----
    h16(*tile)[68] = (h16(*)[68])As;
    int b2 = blockIdx.x - 768;
    int bx = b2 & 63, by = b2 >> 6;
    int r0 = by * 64, c0 = bx * 64;
    int lr = tid >> 4, lc = (tid & 15) * 4;
#pragma unroll
    for (int s = 0; s < 4; ++s) {
      int r = lr + s * 16;
      float4 v = *(const float4*)&w_out[(size_t)(r0 + r) * 4096 + c0 + lc];
      h16x4 hq;
      hq[0] = (h16)v.x; hq[1] = (h16)v.y; hq[2] = (h16)v.z; hq[3] = (h16)v.w;
      *(h16x4*)&tile[r][lc] = hq;
    }
    __syncthreads();
    int oc = tid >> 3, os = (tid & 7) * 8;
#pragma unroll
    for (int s = 0; s < 2; ++s) {
      int c = oc + s * 32;
      h16x8 hv;
#pragma unroll
      for (int e = 0; e < 8; ++e) hv[e] = tile[os + e][c];
      *(h16x8*)&woutT[(size_t)(c0 + c) * 4096 + r0 + os] = hv;
    }
    return;
  }

  // ---- GEMM branch: XCD-chunked (XCD k owns tileM [k*8,k*8+8) x 12 tileN) --
  int lg = (blockIdx.x & 7) * 96 + (blockIdx.x >> 3);
  int tileM = lg / 12, tileN = lg % 12;
  int w = tid >> 6, l = tid & 63, g = l >> 4, t = l & 15;
  int wr = w >> 1, wc = w & 1;
  int lr = l >> 3, lch = l & 7;  // staging: row-in-chunk, chunk idx
  const h16* Abase = A + (size_t)(tileM * 128) * 512;
  const h16* Bbase = Bt + (size_t)(tileN * 128) * 512;
  f32x4 acc[4][4];
#pragma unroll
  for (int i = 0; i < 4; ++i)
#pragma unroll
    for (int j = 0; j < 4; ++j) acc[i][j] = (f32x4){0.f, 0.f, 0.f, 0.f};

  for (int k0 = 0; k0 < 512; k0 += 64) {
#pragma unroll
    for (int c = 0; c < 4; ++c) {
      int chunk = w * 4 + c, row = chunk * 8 + lr;
      int sc = (lch ^ (row & 7)) * 8;  // pre-swizzled source chunk
      gload16(Abase + (size_t)row * 512 + k0 + sc, &As[chunk * 512]);
      gload16(Bbase + (size_t)row * 512 + k0 + sc, &Bs[chunk * 512]);
    }
    __syncthreads();
#pragma unroll
    for (int kk = 0; kk < 64; kk += 32) {
      h16x8 af[4], bfr[4];
#pragma unroll
      for (int mi = 0; mi < 4; ++mi) {
        int rr = wr * 64 + mi * 16 + t, c = (kk >> 3) + g;
        af[mi] = *(const h16x8*)&As[rr * 64 + ((c ^ (rr & 7)) << 3)];
      }
#pragma unroll
      for (int ni = 0; ni < 4; ++ni) {
        int rr = wc * 64 + ni * 16 + t, c = (kk >> 3) + g;
        bfr[ni] = *(const h16x8*)&Bs[rr * 64 + ((c ^ (rr & 7)) << 3)];
      }
#pragma unroll
      for (int mi = 0; mi < 4; ++mi)
#pragma unroll
        for (int ni = 0; ni < 4; ++ni) acc[mi][ni] = MFMA16(af[mi], bfr[ni], acc[mi][ni]);
    }
    __syncthreads();
  }
  // scatter epilogue: C<512 -> Q (scaled by log2e/8), C<1024 -> K, else -> V^T
#pragma unroll
  for (int mi = 0; mi < 4; ++mi) {
#pragma unroll
    for (int ni = 0; ni < 4; ++ni) {
      int C = tileN * 128 + wc * 64 + ni * 16 + t;
#pragma unroll
      for (int r = 0; r < 4; ++r) {
        int R = tileM * 128 + wr * 64 + mi * 16 + 4 * g + r;
        float val = acc[mi][ni][r];
        int b = R >> 10, rm = R & 1023;
        int i = rm >> 3, m = rm & 7;
        int bh8 = b * 8;
        if (C < 512) {
          int h = C >> 6, d = C & 63;
          Qb[((size_t)(bh8 + h) * 8 + m) * 8192 + i * 64 + d] = (h16)(val * 0.18033688f);
        } else if (C < 1024) {
          int c2 = C - 512, h = c2 >> 6, d = c2 & 63;
          Kb[((size_t)(bh8 + h) * 1024 + (m * 128 + i)) * 64 + d] = (h16)val;
        } else {
          int c2 = C - 1024, h = c2 >> 6, d = c2 & 63;
          VbT[((size_t)(bh8 + h) * 64 + d) * 1024 + (m * 128 + i)] = (h16)val;
        }
      }
    }
  }
}

// ---------------- attention (r5 structure, 2 in-loop barriers) -------------
// grid 512; bh = blk&63 (same bh -> same XCD-L2), z = blk>>6.
// 512 threads = 8 waves -> 16 waves/CU at 2 blocks/CU.
// Barrier ledger: prologue B drains Q0/V0. Per m: {QK^T(reads lds_q,
// drained by prev B3) ; softmax ; P-write(ordered after PV(m-1) by B3)} ->
// B2 {drains V[m] DMA; orders P ready} -> Q[m+1]-issue -> PV -> B3 {orders
// PV reads before V-issue & P-write(m+1); drains Q[m+1]} -> V[m+1]-issue.
__global__ __launch_bounds__(512, 4) void k_attn(const h16* __restrict__ Qbuf,
                                                 const h16* __restrict__ Kbuf,
                                                 const h16* __restrict__ VbT,
                                                 h16* __restrict__ Ob) {
  __shared__ __align__(16) h16 lds_q[128 * 64];   // Q_m [i][dh], swizzled, 16KB
  __shared__ __align__(16) h16 lds_v[64 * 128];   // V_m [d][j], swizzled, 16KB
  __shared__ __align__(16) h16 lds_p[128][136];   // P^T [i][j], padded, 34.8KB
  int blk = blockIdx.x;
  int bh = blk & 63, z = blk >> 6;
  int b = bh >> 3, h = bh & 7;
  const h16* Qb = Qbuf + (size_t)bh * 65536;              // [m][i][d]
  const h16* Kz = Kbuf + (size_t)bh * 65536 + z * 8192;   // [j][d]
  const h16* Vb = VbT + (size_t)bh * 65536;               // [d][u=m*128+j]
  int tid = threadIdx.x, w = tid >> 6, l = tid & 63, g = l >> 4, t = l & 15;

  int qs_r0 = l >> 3, qs_ch = l & 7;    // Q: 8 rows/KB, chunk of 8 h16
  int vs_r0 = l >> 4, vs_ch = l & 15;   // V: 4 rows/KB, chunk of 8 h16

  // K fragments in registers, loaded ONCE (z-fixed; wave w owns 16 j-rows)
  h16x8 kf[2];
#pragma unroll
  for (int kk = 0; kk < 2; ++kk)
    kf[kk] = *(const h16x8*)&Kz[(w * 16 + t) * 64 + kk * 32 + g * 8];

  f32x4 oa[4];
#pragma unroll
  for (int dt = 0; dt < 4; ++dt) oa[dt] = (f32x4){0.f, 0.f, 0.f, 0.f};

  // prologue: stage Q_0 and V_0, then one drain barrier
  {
    const h16* Qm = Qb;
#pragma unroll
    for (int s = 0; s < 2; ++s) {
      int r = w * 16 + s * 8 + qs_r0;
      gload16(Qm + r * 64 + ((qs_ch ^ (r & 7)) << 3), &lds_q[(w * 16 + s * 8) * 64]);
    }
#pragma unroll
    for (int s = 0; s < 2; ++s) {
      int r = w * 8 + s * 4 + vs_r0;
      gload16(Vb + (size_t)r * 1024 + ((vs_ch ^ (r & 7)) << 3), &lds_v[(w * 8 + s * 4) * 128]);
    }
  }
  __syncthreads();  // prologue drain: Q0/V0 visible

  for (int m = 0; m < 8; ++m) {
    // T = K_z @ Q_m^T : wave w -> j-rows [w*16,+16) x 128 i-cols
    // (lds_q drained: prologue B for m=0, B3(m-1) otherwise)
    f32x4 accS[8];
#pragma unroll
    for (int nt = 0; nt < 8; ++nt) accS[nt] = (f32x4){0.f, 0.f, 0.f, 0.f};
#pragma unroll
    for (int kk = 0; kk < 2; ++kk)
#pragma unroll
      for (int nt = 0; nt < 8; ++nt) {
        int rr = nt * 16 + t, c = kk * 4 + g;
        h16x8 bq = *(const h16x8*)&lds_q[rr * 64 + ((c ^ (rr & 7)) << 3)];
        accS[nt] = MFMA16(kf[kk], bq, accS[nt]);
      }

    // softmax over i (cols): in-reg over nt + 16 t-lanes via shfl; no max-sub
    float inv[4];
#pragma unroll
    for (int r = 0; r < 4; ++r) {
      float sum = 0.f;
#pragma unroll
      for (int nt = 0; nt < 8; ++nt) {
        float p = exp2f(accS[nt][r]);
        accS[nt][r] = p;
        sum += p;
      }
#pragma unroll
      for (int msk = 1; msk < 16; msk <<= 1) sum += __shfl_xor(sum, msk);
      inv[r] = 1.f / sum;
    }
    // normalize + cvt + P^T write: lds_p[i = nt*16+t][j = w*16+4g+r]
    // (safe: PV(m-1) lds_p reads ordered before here by B3(m-1))
#pragma unroll
    for (int nt = 0; nt < 8; ++nt) {
      h16x4 pk;
#pragma unroll
      for (int r = 0; r < 4; ++r) pk[r] = (h16)(accS[nt][r] * inv[r]);
      *(h16x4*)&lds_p[nt * 16 + t][w * 16 + 4 * g] = pk;
    }
    __syncthreads();  // B2: lds_p ready; lds_q consumed; V[m] DMA drained

    // issue Q[m+1] stage (drains at B3 below, hidden under PV)
    if (m < 7) {
      const h16* Qm = Qb + (m + 1) * 8192;
#pragma unroll
      for (int s = 0; s < 2; ++s) {
        int r = w * 16 + s * 8 + qs_r0;
        gload16(Qm + r * 64 + ((qs_ch ^ (r & 7)) << 3), &lds_q[(w * 16 + s * 8) * 64]);
      }
    }

    // PV: out[i][d] += sum_j P^T[j][i] * V_m[j][d]; wave w -> i-rows [w*16,+16)
#pragma unroll
    for (int kk = 0; kk < 4; ++kk) {
      h16x8 ap = *(const h16x8*)&lds_p[w * 16 + t][kk * 32 + g * 8];
#pragma unroll
      for (int dt = 0; dt < 4; ++dt) {
        int rr = dt * 16 + t, c = kk * 4 + g;
        h16x8 vf = *(const h16x8*)&lds_v[rr * 128 + ((c ^ (rr & 7)) << 3)];
        oa[dt] = MFMA16(ap, vf, oa[dt]);
      }
    }
    __syncthreads();  // B3: PV reads done; Q[m+1] DMA drained

    // issue V[m+1] stage (drains at B2 of m+1, hidden under QK^T+softmax)
    if (m < 7) {
      const h16* Vm = Vb + (m + 1) * 128;
#pragma unroll
      for (int s = 0; s < 2; ++s) {
        int r = w * 8 + s * 4 + vs_r0;
        gload16(Vm + (size_t)r * 1024 + ((vs_ch ^ (r & 7)) << 3), &lds_v[(w * 8 + s * 4) * 128]);
      }
    }
  }

  // store out_z: Ob[b*128 + i][z*512 + h*64 + d]
#pragma unroll
  for (int dt = 0; dt < 4; ++dt)
#pragma unroll
    for (int r = 0; r < 4; ++r) {
      int i = w * 16 + 4 * g + r;
      Ob[(size_t)(b * 128 + i) * 4096 + z * 512 + h * 64 + dt * 16 + t] = (h16)oa[dt][r];
    }
}

// ---------------- final projection GEMM, split-K=4, swizzled staging ------
// A = Ob (1024x4096), Bt = woutT (4096 x 4096). Grid 1024 = 4 blocks/CU.
// XCD k gets tileN in [k*4, k*4+4) -> per-XCD woutT slice 4MB, L2-resident.
__global__ __launch_bounds__(256, 4) void k_final_gemm(const h16* __restrict__ A,
                                                       const h16* __restrict__ Bt,
                                                       h16* __restrict__ P) {
  __shared__ __align__(16) h16 As[128 * 64];
  __shared__ __align__(16) h16 Bs[128 * 64];
  int tid = threadIdx.x;
  int lg = (blockIdx.x & 7) * 128 + (blockIdx.x >> 3);
  int tileN = lg >> 5;        // [xcd*4, xcd*4+4)
  int rem = lg & 31;
  int tileM = rem >> 2, ks = rem & 3;
  int w = tid >> 6, l = tid & 63, g = l >> 4, t = l & 15;
  int wr = w >> 1, wc = w & 1;
  int lr = l >> 3, lch = l & 7;
  const h16* Abase = A + (size_t)(tileM * 128) * 4096 + ks * 1024;
  const h16* Bbase = Bt + (size_t)(tileN * 128) * 4096 + ks * 1024;
  f32x4 acc[4][4];
#pragma unroll
  for (int i = 0; i < 4; ++i)
#pragma unroll
    for (int j = 0; j < 4; ++j) acc[i][j] = (f32x4){0.f, 0.f, 0.f, 0.f};

  for (int k0 = 0; k0 < 1024; k0 += 64) {
#pragma unroll
    for (int c = 0; c < 4; ++c) {
      int chunk = w * 4 + c, row = chunk * 8 + lr;
      int sc = (lch ^ (row & 7)) * 8;  // pre-swizzled source chunk
      gload16(Abase + (size_t)row * 4096 + k0 + sc, &As[chunk * 512]);
      gload16(Bbase + (size_t)row * 4096 + k0 + sc, &Bs[chunk * 512]);
    }
    __syncthreads();
#pragma unroll
    for (int kk = 0; kk < 64; kk += 32) {
      h16x8 af[4], bfr[4];
#pragma unroll
      for (int mi = 0; mi < 4; ++mi) {
        int rr = wr * 64 + mi * 16 + t, c = (kk >> 3) + g;
        af[mi] = *(const h16x8*)&As[rr * 64 + ((c ^ (rr & 7)) << 3)];
      }
#pragma unroll
      for (int ni = 0; ni < 4; ++ni) {
        int rr = wc * 64 + ni * 16 + t, c = (kk >> 3) + g;
        bfr[ni] = *(const h16x8*)&Bs[rr * 64 + ((c ^ (rr & 7)) << 3)];
      }
#pragma unroll
      for (int mi = 0; mi < 4; ++mi)
#pragma unroll
        for (int ni = 0; ni < 4; ++ni) acc[mi][ni] = MFMA16(af[mi], bfr[ni], acc[mi][ni]);
    }
    __syncthreads();
  }
  h16* Pk = P + (size_t)ks * 4194304;
#pragma unroll
  for (int mi = 0; mi < 4; ++mi) {
#pragma unroll
    for (int ni = 0; ni < 4; ++ni) {
      int C = tileN * 128 + wc * 64 + ni * 16 + t;
#pragma unroll
      for (int r = 0; r < 4; ++r) {
        int R = tileM * 128 + wr * 64 + mi * 16 + 4 * g + r;
        Pk[(size_t)R * 4096 + C] = (h16)acc[mi][ni][r];
      }
    }
  }
}

// y = p0+p1+p2+p3 + bias; 8 elems/thread, grid 2048
__global__ __launch_bounds__(256) void k_reduce4(const h16* __restrict__ P,
                                                 const float* __restrict__ bias,
                                                 float* __restrict__ Y) {
  int idx = blockIdx.x * 256 + threadIdx.x;
  size_t base = (size_t)idx * 8;
  h16x8 p0 = *(const h16x8*)&P[base];
  h16x8 p1 = *(const h16x8*)&P[base + 4194304];
  h16x8 p2 = *(const h16x8*)&P[base + 8388608];
  h16x8 p3 = *(const h16x8*)&P[base + 12582912];
  int cb = (int)(base & 4095);
  float4 b0 = *(const float4*)&bias[cb];
  float4 b1 = *(const float4*)&bias[cb + 4];
  float4 o0, o1;
  o0.x = (float)p0[0] + (float)p1[0] + (float)p2[0] + (float)p3[0] + b0.x;
  o0.y = (float)p0[1] + (float)p1[1] + (float)p2[1] + (float)p3[1] + b0.y;
  o0.z = (float)p0[2] + (float)p1[2] + (float)p2[2] + (float)p3[2] + b0.z;
  o0.w = (float)p0[3] + (float)p1[3] + (float)p2[3] + (float)p3[3] + b0.w;
  o1.x = (float)p0[4] + (float)p1[4] + (float)p2[4] + (float)p3[4] + b1.x;
  o1.y = (float)p0[5] + (float)p1[5] + (float)p2[5] + (float)p3[5] + b1.y;
  o1.z = (float)p0[6] + (float)p1[6] + (float)p2[6] + (float)p3[6] + b1.z;
  o1.w = (float)p0[7] + (float)p1[7] + (float)p2[7] + (float)p3[7] + b1.w;
  *(float4*)&Y[base] = o0;
  *(float4*)&Y[base + 4] = o1;
}

// ---------------- launch ----------------

extern "C" void kernel_launch(void* const* d_in, const int* in_sizes, int n_in,
                              void* d_out, int out_size, void* d_ws, size_t ws_size,
                              hipStream_t stream) {
  const float* x = (const float*)d_in[0];
  const float* w_q = (const float*)d_in[1];
  const float* w_kv = (const float*)d_in[2];
  const float* w_out = (const float*)d_in[3];
  const float* b_out = (const float*)d_in[4];
  float* y = (float*)d_out;

  char* ws = (char*)d_ws;
  h16* woutT = (h16*)(ws + 0);          // 32 MB  (alive to the end)
  h16* Ob    = (h16*)(ws + 33554432);   //  8 MB  (alive to the end)
  h16* xh    = (h16*)(ws + 41943040);   //  8 MB  (dead after qkv)
  h16* wqkvT = (h16*)(ws + 50331648);   //  1.5MB (dead after qkv)
  h16* Qb    = (h16*)(ws + 51904512);   //  8 MB  (dead after attn)
  h16* Kb    = (h16*)(ws + 60293120);   //  8 MB  (dead after attn)
  h16* VbT   = (h16*)(ws + 68681728);   //  8 MB  (dead after attn)
  h16* Pp    = (h16*)(ws + 41943040);   // 32 MB partials, overlays dead region
  (void)ws_size; (void)in_sizes; (void)n_in; (void)out_size;

  k_prep_small<<<dim3(2240), dim3(256), 0, stream>>>(x, xh, w_q, w_kv, wqkvT);
  k_qkv_gemm<<<dim3(4864), dim3(256), 0, stream>>>(xh, wqkvT, w_out, Qb, Kb, VbT, woutT);
  k_attn<<<dim3(512), dim3(512), 0, stream>>>(Qb, Kb, VbT, Ob);
  k_final_gemm<<<dim3(1024), dim3(256), 0, stream>>>(Ob, woutT, Pp);
  k_reduce4<<<dim3(2048), dim3(256), 0, stream>>>(Pp, b_out, y);
}